// Round 6
// baseline (11716.383 us; speedup 1.0000x reference)
//
#include <hip/hip_runtime.h>
#include <hip/hip_bf16.h>

#define VOCAB 32000
#define EMBED 512
#define ENCD  512
#define HID   1024
#define ATTN  128
#define SRC   1024
#define TGT   512
#define NB    32          // persistent-kernel blocks
#define NT    1024        // threads per block (16 waves)

typedef __hip_bfloat16 bf16;
typedef _Float16 f16;
typedef __attribute__((ext_vector_type(2))) _Float16 f16x2;
typedef __attribute__((ext_vector_type(8))) _Float16 f16x8;
typedef __attribute__((ext_vector_type(8))) short bf16x8v;
typedef __attribute__((ext_vector_type(4))) float f32x4;

// ---- workspace layout (float offsets), ~24.7 MB ----
#define OFF_ENCPROJ 0           // f32 [1024][128]
#define OFF_G       131072      // f32 [512][4096] PERMUTED gate bases (prow)
#define OFF_HH      2228224     // f32 [513][1024] h history (for k_gemm)
#define OFF_INVDEN  2753536     // f32 [512]
#define OFF_CTXP    2754048     // f32 [32][512] ctx partials        (atomic sc1)
#define OFF_DENP    2770432     // f32 [32] (+pad)                   (atomic sc1)
#define OFF_WAHP    2770560     // f32 [32][128] wah partials        (atomic sc1)
#define OFF_SLOTS   2774656     // u32 [32] barrier slots (+pad)     (atomic sc1)
#define OFF_HPK     2774784     // u32 [512] h packed f16x2          (atomic sc1)
#define OFF_WHH     2775296     // f16 [4096][1024] permuted rows
#define OFF_WIHC    4872448     // f16 [4096][512]  permuted rows
#define OFF_ENCHT   5921024     // f16 [512][1024]  enc TRANSPOSED
// end = 6183168 floats ≈ 24.7 MB

__device__ __forceinline__ float sigm(float x){ return 1.f/(1.f+__expf(-x)); }
__device__ __forceinline__ float tanh_f(float x){
  float ax = fabsf(x);
  float e = __expf(-2.f*ax);
  float r = (1.f - e) / (1.f + e);
  return copysignf(r, x);
}
__device__ __forceinline__ short f2bs(float x){
  union { bf16 h; short s; } u; u.h = __float2bfloat16(x); return u.s;
}
__device__ __forceinline__ bf16x8v cvt8(const float* p){
  float4 a = *reinterpret_cast<const float4*>(p);
  float4 b = *reinterpret_cast<const float4*>(p+4);
  bf16x8v r;
  r[0]=f2bs(a.x); r[1]=f2bs(a.y); r[2]=f2bs(a.z); r[3]=f2bs(a.w);
  r[4]=f2bs(b.x); r[5]=f2bs(b.y); r[6]=f2bs(b.z); r[7]=f2bs(b.w);
  return r;
}

// ---- relaxed agent-scope atomics: sc1 write-through/around L2 to MALL ----
__device__ __forceinline__ float aldf(const float* p){
  return __hip_atomic_load(p, __ATOMIC_RELAXED, __HIP_MEMORY_SCOPE_AGENT);
}
__device__ __forceinline__ void astf(float* p, float v){
  __hip_atomic_store(p, v, __ATOMIC_RELAXED, __HIP_MEMORY_SCOPE_AGENT);
}
__device__ __forceinline__ unsigned aldu(const unsigned* p){
  return __hip_atomic_load(p, __ATOMIC_RELAXED, __HIP_MEMORY_SCOPE_AGENT);
}
__device__ __forceinline__ void astu(unsigned* p, unsigned v){
  __hip_atomic_store(p, v, __ATOMIC_RELAXED, __HIP_MEMORY_SCOPE_AGENT);
}

// ---- grid barrier: NO fences. Ordering: __syncthreads drains vmcnt(0) for
// all waves' sc1 data stores, then flag store; pollers read flag from MALL. ----
__device__ __forceinline__ void gridbar(unsigned* slots, unsigned id, int b, int tid){
  __syncthreads();
  if (tid == 0)
    __hip_atomic_store(&slots[b], id, __ATOMIC_RELAXED, __HIP_MEMORY_SCOPE_AGENT);
  if (tid < 64){
    while (true){
      unsigned v = __hip_atomic_load(&slots[tid & (NB-1)], __ATOMIC_RELAXED, __HIP_MEMORY_SCOPE_AGENT);
      if (__all((int)(v >= id))) break;
      __builtin_amdgcn_s_sleep(1);
    }
  }
  __syncthreads();
}

// ---- one-time: enc_proj[s][a] = enc[s]·Wa_enc[a]  (grid 64 x 128 thr) ----
__global__ void k_encproj(const float* __restrict__ enc, const float* __restrict__ Wa_enc,
                          float* __restrict__ ep){
  __shared__ float eL[16][ENCD];
  int s0 = blockIdx.x*16, tid = threadIdx.x;
  #pragma unroll
  for (int i=0;i<16;i++){
    int li = tid + i*128;
    int t = li>>7, k4 = li&127;
    *reinterpret_cast<float4*>(&eL[t][k4*4]) =
      *reinterpret_cast<const float4*>(enc + (size_t)(s0+t)*ENCD + k4*4);
  }
  __syncthreads();
  const float* w = Wa_enc + (size_t)tid*ENCD;
  float acc[16];
  #pragma unroll
  for (int t=0;t<16;t++) acc[t]=0.f;
  for (int k4=0;k4<128;k4++){
    float4 wv = *reinterpret_cast<const float4*>(w + k4*4);
    #pragma unroll
    for (int t=0;t<16;t++){
      float4 e4 = *reinterpret_cast<const float4*>(&eL[t][k4*4]);
      acc[t] += wv.x*e4.x + wv.y*e4.y + wv.z*e4.z + wv.w*e4.w;
    }
  }
  #pragma unroll
  for (int t=0;t<16;t++) ep[(size_t)(s0+t)*ATTN + tid] = acc[t];
}

// ---- one-time: Gp[t][prow] = b_ih+b_hh + W_ih[:,0:512]·emb, prow-permuted ----
__global__ void k_gbase(const int* __restrict__ sos, const int* __restrict__ tgt,
                        const float* __restrict__ embt, const float* __restrict__ W_ih,
                        const float* __restrict__ b_ih, const float* __restrict__ b_hh,
                        float* __restrict__ Gp){
  __shared__ float eL[16][EMBED];
  int tid = threadIdx.x;
  int t0 = blockIdx.y*16;
  #pragma unroll
  for (int i=0;i<8;i++){
    int li = tid + i*256;
    int t = li>>7, k4 = li&127;
    int tg = t0 + t;
    int tok = (tg==0) ? sos[0] : tgt[tg-1];
    *reinterpret_cast<float4*>(&eL[t][k4*4]) =
      *reinterpret_cast<const float4*>(embt + (size_t)tok*EMBED + k4*4);
  }
  __syncthreads();
  int r = blockIdx.x*256 + tid;
  int g = r>>10, j = r&1023;
  int prow = (j>>5)*128 + g*32 + (j&31);
  const float* w = W_ih + (size_t)r*(EMBED+ENCD);
  float base = b_ih[r] + b_hh[r];
  float acc[16];
  #pragma unroll
  for (int t=0;t<16;t++) acc[t]=0.f;
  for (int k4=0;k4<128;k4++){
    float4 wv = *reinterpret_cast<const float4*>(w + k4*4);
    #pragma unroll
    for (int t=0;t<16;t++){
      float4 e4 = *reinterpret_cast<const float4*>(&eL[t][k4*4]);
      acc[t] += wv.x*e4.x + wv.y*e4.y + wv.z*e4.z + wv.w*e4.w;
    }
  }
  #pragma unroll
  for (int t=0;t<16;t++) Gp[(size_t)(t0+t)*4096 + prow] = acc[t] + base;
}

// ---- one-time f16 conversions, permuted: prow = (j>>5)*128 + g*32 + (j&31) ----
__global__ void k_cvt_whh(const float* __restrict__ W, f16* __restrict__ out){
  int r = blockIdx.x;
  int g = r >> 10, j = r & 1023;
  int prow = (j>>5)*128 + g*32 + (j&31);
  int k0 = threadIdx.x*8;
  float4 a = *reinterpret_cast<const float4*>(W + (size_t)r*HID + k0);
  float4 c = *reinterpret_cast<const float4*>(W + (size_t)r*HID + k0 + 4);
  f16x8 v = { (f16)a.x,(f16)a.y,(f16)a.z,(f16)a.w,(f16)c.x,(f16)c.y,(f16)c.z,(f16)c.w };
  *reinterpret_cast<f16x8*>(out + (size_t)prow*HID + k0) = v;
}
__global__ void k_cvt_wihc(const float* __restrict__ W, f16* __restrict__ out){
  int r = blockIdx.x;
  int g = r >> 10, j = r & 1023;
  int prow = (j>>5)*128 + g*32 + (j&31);
  int k0 = threadIdx.x*8;
  float4 a = *reinterpret_cast<const float4*>(W + (size_t)r*(EMBED+ENCD) + EMBED + k0);
  float4 c = *reinterpret_cast<const float4*>(W + (size_t)r*(EMBED+ENCD) + EMBED + k0 + 4);
  f16x8 v = { (f16)a.x,(f16)a.y,(f16)a.z,(f16)a.w,(f16)c.x,(f16)c.y,(f16)c.z,(f16)c.w };
  *reinterpret_cast<f16x8*>(out + (size_t)prow*ENCD + k0) = v;
}
// enc [1024][512] f32 -> encT_h [512][1024] f16 (tiled transpose)
__global__ void k_cvt_encT(const float* __restrict__ enc, f16* __restrict__ out){
  __shared__ float tile[64][65];
  int s0 = blockIdx.x*64, d0 = blockIdx.y*64;
  int tid = threadIdx.x;
  #pragma unroll
  for (int i=0;i<16;i++){
    int idx = tid + i*256;
    int sl = idx>>6, dl = idx&63;
    tile[sl][dl] = enc[(size_t)(s0+sl)*ENCD + d0+dl];
  }
  __syncthreads();
  #pragma unroll
  for (int i=0;i<16;i++){
    int idx = tid + i*256;
    int dl = idx>>6, sl = idx&63;
    out[(size_t)(d0+dl)*SRC + s0+sl] = (f16)tile[sl][dl];
  }
}

// ---- one-time: slots=0, Hh[0]=h0, hpk=pack(h0), wahp step-0 (grid 32 x 128) ----
__global__ void k_prep0(const float* __restrict__ h0, const float* __restrict__ Wa_h,
                        float* __restrict__ Hh, float* __restrict__ wahp,
                        unsigned* __restrict__ slots, unsigned* __restrict__ hpk){
  int b = blockIdx.x, tid = threadIdx.x;
  if (b == 0 && tid < NB) slots[tid] = 0u;
  if (b < 8) Hh[b*128 + tid] = h0[b*128 + tid];
  if (tid < 16){
    union { unsigned u; f16x2 h; } cv;
    cv.h = (f16x2){ (f16)h0[b*32 + 2*tid], (f16)h0[b*32 + 2*tid + 1] };
    hpk[b*16 + tid] = cv.u;
  }
  __shared__ float hl[32];
  if (tid < 32) hl[tid] = h0[b*32 + tid];
  __syncthreads();
  const float* wr = Wa_h + (size_t)tid*HID + b*32;
  float acc = 0.f;
  #pragma unroll
  for (int i4=0;i4<8;i4++){
    float4 w4 = *reinterpret_cast<const float4*>(wr + i4*4);
    acc += w4.x*hl[i4*4] + w4.y*hl[i4*4+1] + w4.z*hl[i4*4+2] + w4.w*hl[i4*4+3];
  }
  wahp[b*128 + tid] = acc;
}

// ---- persistent recurrence kernel: 32 blocks x 1024 thr (16 waves/CU) ----
__global__ __launch_bounds__(NT) void k_loop(
    const f16* __restrict__ Whh_h, const f16* __restrict__ Wihc_h,
    const f16* __restrict__ encT_h, const float* __restrict__ encp,
    const float* __restrict__ Wa_h, const float* __restrict__ Gp,
    float* __restrict__ Hh, float* __restrict__ Pout,
    float* __restrict__ ctxp, float* __restrict__ denp,
    float* __restrict__ wahp, float* __restrict__ invd,
    unsigned* __restrict__ slots, unsigned* __restrict__ hpk,
    const float* __restrict__ c0, const float* __restrict__ v_a)
{
  const int b = blockIdx.x, tid = threadIdx.x;
  __shared__ f16x2 hs2[512];        // h_t as f16 pairs
  __shared__ float wp[2][128];      // wah partial sums
  __shared__ float vas[128];
  __shared__ float ps[32];          // unnormalized p for this block's rows
  __shared__ float gld[128];        // G row slice
  __shared__ float gacc[128];       // Whh·h
  __shared__ float cp2[2][512];
  __shared__ f16x2 cs2[256];        // normalized ctx as f16 pairs
  __shared__ float g2[128];
  __shared__ float cst[32];         // c state slice
  __shared__ float hnl[32];
  __shared__ float invs;

  if (tid < 128) vas[tid] = v_a[tid];
  if (tid < 32)  cst[tid] = c0[b*32 + tid];

  const int l8 = tid >> 3, q8 = tid & 7;   // matvec: 128 rows x 8 lanes
  const f16x8* wA = (const f16x8*)(Whh_h  + ((size_t)(b*128 + l8))*HID  + q8*128);
  const f16x8* wB = (const f16x8*)(Wihc_h + ((size_t)(b*128 + l8))*ENCD + q8*64);
  const int srow = tid >> 5, slq = tid & 31;   // scores: 32 rows x 32 lanes
  const int sg = b*32 + srow;

  for (int t = 0; t < TGT; ++t){
    // ---- A0: hpk load (MALL) | wahp reduce (MALL) | G preload (L2-hot) ----
    if (tid < 512){
      union { unsigned u; f16x2 h; } cv;
      cv.u = aldu(&hpk[tid]);
      hs2[tid] = cv.h;
    } else if (tid < 768){
      int idx = tid - 512, a = idx & 127, g = idx >> 7;   // 2 groups of 16 partials
      float acc = 0.f;
      #pragma unroll
      for (int p = 0; p < 16; ++p) acc += aldf(&wahp[(g*16+p)*128 + a]);
      wp[g][a] = acc;
    } else if (tid < 896){
      gld[tid-768] = Gp[(size_t)t*4096 + b*128 + (tid-768)];
    }
    __syncthreads();
    // ---- A1: scores (32 rows, 32 lanes each, 4 attn dims/lane) ----
    {
      float4 e4 = *reinterpret_cast<const float4*>(encp + (size_t)sg*ATTN + slq*4);
      float sc = 0.f;
      #pragma unroll
      for (int u = 0; u < 4; ++u){
        int a = slq*4 + u;
        float wa = wp[0][a] + wp[1][a];
        sc += vas[a]*tanh_f((&e4.x)[u] + wa);
      }
      sc += __shfl_xor(sc,1); sc += __shfl_xor(sc,2); sc += __shfl_xor(sc,4);
      sc += __shfl_xor(sc,8); sc += __shfl_xor(sc,16);
      if (slq == 0){
        float pv = __expf(sc);
        ps[srow] = pv;
        Pout[(size_t)t*SRC + sg] = pv;
      }
    }
    __syncthreads();
    // ---- A2: ctx partials (contiguous via encT) + den partial ----
    if (tid < 512){
      const f16x8* er = (const f16x8*)(encT_h + (size_t)tid*SRC + b*32);
      float a0 = 0.f;
      #pragma unroll
      for (int i = 0; i < 4; ++i){
        f16x8 ev = er[i];
        #pragma unroll
        for (int u = 0; u < 8; ++u) a0 += ps[i*8+u] * (float)ev[u];
      }
      astf(&ctxp[b*512 + tid], a0);
    } else if (tid < 576){
      float v = (tid < 544) ? ps[tid-512] : 0.f;
      v += __shfl_xor(v,1); v += __shfl_xor(v,2); v += __shfl_xor(v,4);
      v += __shfl_xor(v,8); v += __shfl_xor(v,16);
      if (tid == 512) astf(&denp[b], v);
    }
    // ---- A3: gacc = Whh·h (L2-hot weights; hides barrier skew) ----
    {
      float acc = 0.f;
      #pragma unroll
      for (int i = 0; i < 16; ++i){
        f16x8 wv = wA[i];
        const f16x2* wpp = (const f16x2*)&wv;
        int k2 = q8*64 + i*4;
        acc = __builtin_amdgcn_fdot2(wpp[0], hs2[k2+0], acc, false);
        acc = __builtin_amdgcn_fdot2(wpp[1], hs2[k2+1], acc, false);
        acc = __builtin_amdgcn_fdot2(wpp[2], hs2[k2+2], acc, false);
        acc = __builtin_amdgcn_fdot2(wpp[3], hs2[k2+3], acc, false);
      }
      acc += __shfl_xor(acc,1); acc += __shfl_xor(acc,2); acc += __shfl_xor(acc,4);
      if (q8 == 0) gacc[l8] = acc;
    }
    gridbar(slots, 2u*t+1u, b, tid);
    // ---- B0: den reduce + ctx reduce (MALL) ----
    if (tid < 64){
      float dv = (tid < 32) ? aldf(&denp[tid]) : 0.f;
      dv += __shfl_xor(dv,1); dv += __shfl_xor(dv,2); dv += __shfl_xor(dv,4);
      dv += __shfl_xor(dv,8); dv += __shfl_xor(dv,16);
      if (tid == 0){ float iv = 1.f/dv; invs = iv; if (b == 0) invd[t] = iv; }
    }
    {
      int d = tid & 511, g = tid >> 9;    // 2 groups of 16 partials
      float a0 = 0.f;
      #pragma unroll
      for (int p = 0; p < 16; ++p) a0 += aldf(&ctxp[(g*16+p)*512 + d]);
      cp2[g][d] = a0;
    }
    __syncthreads();
    if (tid < 256){
      float inv = invs;
      int d2 = tid*2;
      cs2[tid] = (f16x2){ (f16)((cp2[0][d2]+cp2[1][d2])*inv),
                          (f16)((cp2[0][d2+1]+cp2[1][d2+1])*inv) };
    }
    __syncthreads();
    // ---- B1: gates = gacc + Wihc·ctx + G ----
    {
      float acc = 0.f;
      #pragma unroll
      for (int i = 0; i < 8; ++i){
        f16x8 wv = wB[i];
        const f16x2* wpp = (const f16x2*)&wv;
        int k2 = q8*32 + i*4;
        acc = __builtin_amdgcn_fdot2(wpp[0], cs2[k2+0], acc, false);
        acc = __builtin_amdgcn_fdot2(wpp[1], cs2[k2+1], acc, false);
        acc = __builtin_amdgcn_fdot2(wpp[2], cs2[k2+2], acc, false);
        acc = __builtin_amdgcn_fdot2(wpp[3], cs2[k2+3], acc, false);
      }
      acc += __shfl_xor(acc,1); acc += __shfl_xor(acc,2); acc += __shfl_xor(acc,4);
      if (q8 == 0) g2[l8] = acc + gacc[l8] + gld[l8];
    }
    __syncthreads();
    // ---- B2: LSTM pointwise (32 j-dims) ----
    if (tid < 32){
      float gi = g2[tid], gf = g2[32+tid], gg = g2[64+tid], go = g2[96+tid];
      float cn = sigm(gf)*cst[tid] + sigm(gi)*tanh_f(gg);
      float hn = sigm(go)*tanh_f(cn);
      cst[tid] = cn; hnl[tid] = hn;
      Hh[(size_t)(t+1)*HID + b*32 + tid] = hn;   // normal store, for k_gemm
    }
    __syncthreads();
    // ---- B3: hpk pack + wahp partials ----
    if (tid < 16){
      union { unsigned u; f16x2 h; } cv;
      cv.h = (f16x2){ (f16)hnl[2*tid], (f16)hnl[2*tid+1] };
      astu(&hpk[b*16 + tid], cv.u);
    }
    if (tid < 128){
      const float* wr = Wa_h + (size_t)tid*HID + b*32;
      float acc = 0.f;
      #pragma unroll
      for (int i4 = 0; i4 < 8; ++i4){
        float4 w4 = *reinterpret_cast<const float4*>(wr + i4*4);
        acc += w4.x*hnl[i4*4] + w4.y*hnl[i4*4+1] + w4.z*hnl[i4*4+2] + w4.w*hnl[i4*4+3];
      }
      astf(&wahp[b*128 + tid], acc);
    }
    gridbar(slots, 2u*t+2u, b, tid);
  }
}

// ---- epilogue: logits = H @ W_out^T + b_out (bf16 MFMA, f32 in/out) ----
__global__ __launch_bounds__(256) void k_gemm(const float* __restrict__ A, const float* __restrict__ B,
                                              const float* __restrict__ bias, float* __restrict__ C){
  int bn = blockIdx.x, bm = blockIdx.y;
  int tid = threadIdx.x;
  int wid = tid>>6, lane = tid&63;
  int wr = wid>>1, wc = wid&1;
  int rowf = lane&15, kg = lane>>4;
  const int m_base = bm*128 + wr*64;
  const int n_base = bn*128 + wc*64;
  const float* Ap = A + (size_t)(m_base + rowf)*HID + kg*8;
  const float* Bp = B + (size_t)(n_base + rowf)*HID + kg*8;
  f32x4 acc[4][4];
  #pragma unroll
  for (int i=0;i<4;i++)
    #pragma unroll
    for (int jv=0;jv<4;jv++) acc[i][jv] = (f32x4){0.f,0.f,0.f,0.f};
  for (int kk=0; kk<HID; kk+=32){
    bf16x8v av[4], bv[4];
    #pragma unroll
    for (int mt=0;mt<4;mt++) av[mt] = cvt8(Ap + (size_t)mt*16*HID + kk);
    #pragma unroll
    for (int nt=0;nt<4;nt++) bv[nt] = cvt8(Bp + (size_t)nt*16*HID + kk);
    #pragma unroll
    for (int mt=0;mt<4;mt++)
      #pragma unroll
      for (int nt=0;nt<4;nt++)
        acc[mt][nt] = __builtin_amdgcn_mfma_f32_16x16x32_bf16(av[mt], bv[nt], acc[mt][nt], 0,0,0);
  }
  #pragma unroll
  for (int mt=0;mt<4;mt++){
    #pragma unroll
    for (int nt=0;nt<4;nt++){
      int n = n_base + nt*16 + rowf;
      float bo = bias[n];
      #pragma unroll
      for (int i=0;i<4;i++){
        int m = m_base + mt*16 + kg*4 + i;
        C[(size_t)m*VOCAB + n] = acc[mt][nt][i] + bo;
      }
    }
  }
}

// ---- epilogue: attn = P * invden, in place on d_out ----
__global__ void k_attnorm(float* __restrict__ out, const float* __restrict__ invden){
  int idx = blockIdx.x*256 + threadIdx.x;
  out[idx] = out[idx]*invden[idx>>10];
}

extern "C" void kernel_launch(void* const* d_in, const int* in_sizes, int n_in,
                              void* d_out, int out_size, void* d_ws, size_t ws_size,
                              hipStream_t stream){
  const float* enc    = (const float*)d_in[0];
  const float* h0     = (const float*)d_in[1];
  const float* c0     = (const float*)d_in[2];
  const int*   sos    = (const int*)d_in[3];
  const int*   tgt    = (const int*)d_in[4];
  const float* embt   = (const float*)d_in[5];
  const float* Wa_enc = (const float*)d_in[6];
  const float* Wa_h   = (const float*)d_in[7];
  const float* v_a    = (const float*)d_in[8];
  const float* W_ih   = (const float*)d_in[9];
  const float* W_hh   = (const float*)d_in[10];
  const float* b_ih   = (const float*)d_in[11];
  const float* b_hh   = (const float*)d_in[12];
  const float* W_out  = (const float*)d_in[13];
  const float* b_out  = (const float*)d_in[14];

  float* ws    = (float*)d_ws;
  float* encp  = ws + OFF_ENCPROJ;
  float* Gp    = ws + OFF_G;
  float* Hh    = ws + OFF_HH;
  float* invd  = ws + OFF_INVDEN;
  float* ctxp  = ws + OFF_CTXP;
  float* denp  = ws + OFF_DENP;
  float* wahp  = ws + OFF_WAHP;
  unsigned* slots = (unsigned*)(ws + OFF_SLOTS);
  unsigned* hpk   = (unsigned*)(ws + OFF_HPK);
  f16* Whh_h   = (f16*)(ws + OFF_WHH);
  f16* Wihc_h  = (f16*)(ws + OFF_WIHC);
  f16* encT_h  = (f16*)(ws + OFF_ENCHT);

  float* out_logits = (float*)d_out;
  float* out_attn   = out_logits + (size_t)TGT*VOCAB;

  k_encproj <<<64, 128, 0, stream>>>(enc, Wa_enc, encp);
  k_gbase   <<<dim3(16, 32), 256, 0, stream>>>(sos, tgt, embt, W_ih, b_ih, b_hh, Gp);
  k_cvt_whh <<<4096, 128, 0, stream>>>(W_hh, Whh_h);
  k_cvt_wihc<<<4096, 64, 0, stream>>>(W_ih, Wihc_h);
  k_cvt_encT<<<dim3(16, 8), 256, 0, stream>>>(enc, encT_h);
  k_prep0   <<<NB, 128, 0, stream>>>(h0, Wa_h, Hh, wahp, slots, hpk);

  k_loop<<<NB, NT, 0, stream>>>(Whh_h, Wihc_h, encT_h, encp, Wa_h, Gp,
                                Hh, out_attn, ctxp, denp, wahp, invd,
                                slots, hpk, c0, v_a);

  k_gemm   <<<dim3(250, 4), 256, 0, stream>>>(Hh + HID, W_out, b_out, out_logits);
  k_attnorm<<<2048, 256, 0, stream>>>(out_attn, invd);
}

// Round 7
// 9552.440 us; speedup vs baseline: 1.2265x; 1.2265x over previous
//
#include <hip/hip_runtime.h>
#include <hip/hip_bf16.h>

#define VOCAB 32000
#define EMBED 512
#define ENCD  512
#define HID   1024
#define ATTN  128
#define SRC   1024
#define TGT   512
#define NBA   8           // attention blocks
#define NBS   64          // step blocks

typedef __hip_bfloat16 bf16;
typedef _Float16 f16;
typedef __attribute__((ext_vector_type(2))) _Float16 f16x2;
typedef __attribute__((ext_vector_type(8))) _Float16 f16x8;
typedef __attribute__((ext_vector_type(8))) short bf16x8v;
typedef __attribute__((ext_vector_type(4))) float f32x4;

// ---- workspace layout (float offsets), ~24.4 MB ----
#define OFF_EPH     0           // f16 [1024][128] enc_proj
#define OFF_G       65536       // f32 [512][4096] PERMUTED gate bases
#define OFF_HH      2162688     // f32 [513][1024] h history
#define OFF_CC      2688000     // f32 [1024] c state
#define OFF_INVD    2689024     // f32 [512]
#define OFF_CTXP    2689536     // f32 [8][512] ctx partials
#define OFF_DENP    2693632     // f32 [8] (+pad 32)
#define OFF_WAHP    2693664     // f32 [64][128] wah partials
#define OFF_PROBE   2701856     // u32 [32] probe slots (+pad 64)
#define OFF_WHH     2701920     // f16 [4096][1024] permuted rows
#define OFF_WIHC    4799072     // f16 [4096][512]  permuted rows
#define OFF_ENCH    5847648     // f16 [1024][512]  enc row-major
// end = 6109792 floats = 24.4 MB

__device__ __forceinline__ float sigm(float x){ return 1.f/(1.f+__expf(-x)); }
__device__ __forceinline__ float tanh_f(float x){
  float ax = fabsf(x);
  float e = __expf(-2.f*ax);
  float r = (1.f - e) / (1.f + e);
  return copysignf(r, x);
}
__device__ __forceinline__ short f2bs(float x){
  union { bf16 h; short s; } u; u.h = __float2bfloat16(x); return u.s;
}
__device__ __forceinline__ bf16x8v cvt8(const float* p){
  float4 a = *reinterpret_cast<const float4*>(p);
  float4 b = *reinterpret_cast<const float4*>(p+4);
  bf16x8v r;
  r[0]=f2bs(a.x); r[1]=f2bs(a.y); r[2]=f2bs(a.z); r[3]=f2bs(a.w);
  r[4]=f2bs(b.x); r[5]=f2bs(b.y); r[6]=f2bs(b.z); r[7]=f2bs(b.w);
  return r;
}

// ---- one-time: enc_proj[s][a] -> f16 (grid 64 x 128 thr) ----
__global__ void k_encproj(const float* __restrict__ enc, const float* __restrict__ Wa_enc,
                          f16* __restrict__ eph){
  __shared__ float eL[16][ENCD];
  int s0 = blockIdx.x*16, tid = threadIdx.x;
  #pragma unroll
  for (int i=0;i<16;i++){
    int li = tid + i*128;
    int t = li>>7, k4 = li&127;
    *reinterpret_cast<float4*>(&eL[t][k4*4]) =
      *reinterpret_cast<const float4*>(enc + (size_t)(s0+t)*ENCD + k4*4);
  }
  __syncthreads();
  const float* w = Wa_enc + (size_t)tid*ENCD;
  float acc[16];
  #pragma unroll
  for (int t=0;t<16;t++) acc[t]=0.f;
  for (int k4=0;k4<128;k4++){
    float4 wv = *reinterpret_cast<const float4*>(w + k4*4);
    #pragma unroll
    for (int t=0;t<16;t++){
      float4 e4 = *reinterpret_cast<const float4*>(&eL[t][k4*4]);
      acc[t] += wv.x*e4.x + wv.y*e4.y + wv.z*e4.z + wv.w*e4.w;
    }
  }
  #pragma unroll
  for (int t=0;t<16;t++) eph[(size_t)(s0+t)*ATTN + tid] = (f16)acc[t];
}

// ---- one-time: Gp[t][prow] = b_ih+b_hh + W_ih[:,0:512]·emb ; prow=(j>>4)*64+g*16+(j&15) ----
__global__ void k_gbase(const int* __restrict__ sos, const int* __restrict__ tgt,
                        const float* __restrict__ embt, const float* __restrict__ W_ih,
                        const float* __restrict__ b_ih, const float* __restrict__ b_hh,
                        float* __restrict__ Gp){
  __shared__ float eL[16][EMBED];
  int tid = threadIdx.x;
  int t0 = blockIdx.y*16;
  #pragma unroll
  for (int i=0;i<8;i++){
    int li = tid + i*256;
    int t = li>>7, k4 = li&127;
    int tg = t0 + t;
    int tok = (tg==0) ? sos[0] : tgt[tg-1];
    *reinterpret_cast<float4*>(&eL[t][k4*4]) =
      *reinterpret_cast<const float4*>(embt + (size_t)tok*EMBED + k4*4);
  }
  __syncthreads();
  int r = blockIdx.x*256 + tid;
  int g = r>>10, j = r&1023;
  int prow = (j>>4)*64 + g*16 + (j&15);
  const float* w = W_ih + (size_t)r*(EMBED+ENCD);
  float base = b_ih[r] + b_hh[r];
  float acc[16];
  #pragma unroll
  for (int t=0;t<16;t++) acc[t]=0.f;
  for (int k4=0;k4<128;k4++){
    float4 wv = *reinterpret_cast<const float4*>(w + k4*4);
    #pragma unroll
    for (int t=0;t<16;t++){
      float4 e4 = *reinterpret_cast<const float4*>(&eL[t][k4*4]);
      acc[t] += wv.x*e4.x + wv.y*e4.y + wv.z*e4.z + wv.w*e4.w;
    }
  }
  #pragma unroll
  for (int t=0;t<16;t++) Gp[(size_t)(t0+t)*4096 + prow] = acc[t] + base;
}

// ---- one-time f16 conversions, permuted rows: prow = (j>>4)*64 + g*16 + (j&15) ----
__global__ void k_cvt_whh(const float* __restrict__ W, f16* __restrict__ out){
  int r = blockIdx.x;
  int g = r >> 10, j = r & 1023;
  int prow = (j>>4)*64 + g*16 + (j&15);
  int k0 = threadIdx.x*8;
  float4 a = *reinterpret_cast<const float4*>(W + (size_t)r*HID + k0);
  float4 c = *reinterpret_cast<const float4*>(W + (size_t)r*HID + k0 + 4);
  f16x8 v = { (f16)a.x,(f16)a.y,(f16)a.z,(f16)a.w,(f16)c.x,(f16)c.y,(f16)c.z,(f16)c.w };
  *reinterpret_cast<f16x8*>(out + (size_t)prow*HID + k0) = v;
}
__global__ void k_cvt_wihc(const float* __restrict__ W, f16* __restrict__ out){
  int r = blockIdx.x;
  int g = r >> 10, j = r & 1023;
  int prow = (j>>4)*64 + g*16 + (j&15);
  int k0 = threadIdx.x*8;
  float4 a = *reinterpret_cast<const float4*>(W + (size_t)r*(EMBED+ENCD) + EMBED + k0);
  float4 c = *reinterpret_cast<const float4*>(W + (size_t)r*(EMBED+ENCD) + EMBED + k0 + 4);
  f16x8 v = { (f16)a.x,(f16)a.y,(f16)a.z,(f16)a.w,(f16)c.x,(f16)c.y,(f16)c.z,(f16)c.w };
  *reinterpret_cast<f16x8*>(out + (size_t)prow*ENCD + k0) = v;
}
__global__ void k_cvt_ench(const float* __restrict__ enc, f16* __restrict__ out){
  int s = blockIdx.x;
  int k0 = threadIdx.x*8;
  float4 a = *reinterpret_cast<const float4*>(enc + (size_t)s*ENCD + k0);
  float4 c = *reinterpret_cast<const float4*>(enc + (size_t)s*ENCD + k0 + 4);
  f16x8 v = { (f16)a.x,(f16)a.y,(f16)a.z,(f16)a.w,(f16)c.x,(f16)c.y,(f16)c.z,(f16)c.w };
  *reinterpret_cast<f16x8*>(out + (size_t)s*ENCD + k0) = v;
}

// ---- one-time: Hh[0]=h0, Cc=c0, wahp step-0, probe slots (grid 64 x 128) ----
__global__ void k_prep0(const float* __restrict__ h0, const float* __restrict__ c0,
                        const float* __restrict__ Wa_h, float* __restrict__ Hh,
                        float* __restrict__ Cc, float* __restrict__ wahp,
                        unsigned* __restrict__ pslots){
  int b = blockIdx.x, tid = threadIdx.x;
  if (b == 0 && tid < 32) pslots[tid] = 0u;
  if (b < 8){ Hh[b*128 + tid] = h0[b*128 + tid]; Cc[b*128 + tid] = c0[b*128 + tid]; }
  __shared__ float hl[16];
  if (tid < 16) hl[tid] = h0[b*16 + tid];
  __syncthreads();
  const float* wr = Wa_h + (size_t)tid*HID + b*16;
  float a = 0.f;
  #pragma unroll
  for (int i4=0;i4<4;i4++){
    float4 w4 = *reinterpret_cast<const float4*>(wr + i4*4);
    a += w4.x*hl[i4*4] + w4.y*hl[i4*4+1] + w4.z*hl[i4*4+2] + w4.w*hl[i4*4+3];
  }
  wahp[b*128 + tid] = a;
}

// ---- µbench: 128 pure flag-barriers across 32 blocks (dur/128 = barrier cost) ----
__global__ __launch_bounds__(256) void k_barprobe(unsigned* __restrict__ slots){
  int b = blockIdx.x, tid = threadIdx.x;
  for (unsigned id = 1; id <= 128; ++id){
    __syncthreads();
    if (tid == 0)
      __hip_atomic_store(&slots[b], id, __ATOMIC_RELAXED, __HIP_MEMORY_SCOPE_AGENT);
    if (tid < 64){
      while (true){
        unsigned v = __hip_atomic_load(&slots[tid & 31], __ATOMIC_RELAXED, __HIP_MEMORY_SCOPE_AGENT);
        if (__all((int)(v >= id))) break;
        __builtin_amdgcn_s_sleep(1);
      }
    }
    __syncthreads();
  }
}

// ---- per step: attention (grid 8 x 1024 thr) ----
__global__ __launch_bounds__(1024) void k_attn(int t,
    const f16* __restrict__ eph, const f16* __restrict__ enc_h,
    const float* __restrict__ v_a, const float* __restrict__ wahp,
    float* __restrict__ Pout, float* __restrict__ ctxp, float* __restrict__ denp)
{
  const int b = blockIdx.x, tid = threadIdx.x;
  __shared__ float wp4[4][128];
  __shared__ float vas[128];
  __shared__ float ps[128];
  if (tid < 512){
    int a = tid & 127, g = tid >> 7;
    float acc = 0.f;
    #pragma unroll
    for (int p = 0; p < 16; ++p) acc += wahp[(g*16+p)*128 + a];
    wp4[g][a] = acc;
  } else if (tid >= 896 && tid < 1024 - 0){
    if (tid < 1024 && tid - 896 < 128) vas[tid-896] = v_a[tid-896];
  }
  __syncthreads();
  {
    int srow = tid >> 3, q = tid & 7;                 // 128 rows x 8 lanes
    const f16x8* ep = (const f16x8*)(eph + (size_t)(b*128+srow)*ATTN + q*16);
    f16x8 e0 = ep[0], e1 = ep[1];
    float sc = 0.f;
    #pragma unroll
    for (int u = 0; u < 8; ++u){
      int a0 = q*16 + u, a1 = q*16 + 8 + u;
      float wa0 = wp4[0][a0]+wp4[1][a0]+wp4[2][a0]+wp4[3][a0];
      float wa1 = wp4[0][a1]+wp4[1][a1]+wp4[2][a1]+wp4[3][a1];
      sc += vas[a0]*tanh_f((float)e0[u] + wa0);
      sc += vas[a1]*tanh_f((float)e1[u] + wa1);
    }
    sc += __shfl_xor(sc,1); sc += __shfl_xor(sc,2); sc += __shfl_xor(sc,4);
    if (q == 0){
      float pv = __expf(sc);
      ps[srow] = pv;
      Pout[(size_t)t*SRC + b*128 + srow] = pv;
    }
  }
  __syncthreads();
  if (tid < 256){
    const f16x2* e2 = (const f16x2*)enc_h;            // [1024][256] f16 pairs
    float a0 = 0.f, a1 = 0.f;
    #pragma unroll 8
    for (int s = 0; s < 128; ++s){
      f16x2 ev = e2[(size_t)(b*128+s)*256 + tid];
      float pv = ps[s];
      a0 += pv*(float)ev[0]; a1 += pv*(float)ev[1];
    }
    *reinterpret_cast<float2*>(ctxp + b*512 + tid*2) = make_float2(a0, a1);
  } else if (tid >= 960){
    float v = ps[tid-960] + ps[tid-896];
    v += __shfl_xor(v,1); v += __shfl_xor(v,2); v += __shfl_xor(v,4);
    v += __shfl_xor(v,8); v += __shfl_xor(v,16); v += __shfl_xor(v,32);
    if (tid == 960) denp[b] = v;
  }
}

// ---- per step: ctx reduce + gates + LSTM + wahp (grid 64 x 512 thr) ----
__global__ __launch_bounds__(512) void k_step(int t,
    const f16* __restrict__ Whh_h, const f16* __restrict__ Wihc_h,
    const float* __restrict__ Wa_h, const float* __restrict__ Gp,
    const float* __restrict__ ctxp, const float* __restrict__ denp,
    float* __restrict__ Hh, float* __restrict__ Cc,
    float* __restrict__ wahp, float* __restrict__ invd)
{
  const int b = blockIdx.x, tid = threadIdx.x;
  __shared__ f16x2 hs2[512];
  __shared__ float cpr[512];
  __shared__ f16x2 cs2[256];
  __shared__ float g2[64];
  __shared__ float hnl[16];
  __shared__ float invs;

  if (tid < 256){
    float4 v0 = *reinterpret_cast<const float4*>(Hh + (size_t)t*HID + tid*4);
    hs2[tid*2]   = (f16x2){(f16)v0.x,(f16)v0.y};
    hs2[tid*2+1] = (f16x2){(f16)v0.z,(f16)v0.w};
  } else {
    int d2 = (tid-256)*2;
    float a0 = 0.f, a1 = 0.f;
    #pragma unroll
    for (int p = 0; p < 8; ++p){
      float2 v = *reinterpret_cast<const float2*>(ctxp + p*512 + d2);
      a0 += v.x; a1 += v.y;
    }
    cpr[d2] = a0; cpr[d2+1] = a1;
  }
  if (tid == 0){
    float dv = 0.f;
    #pragma unroll
    for (int p = 0; p < 8; ++p) dv += denp[p];
    float iv = 1.f/dv; invs = iv;
    if (b == 0) invd[t] = iv;
  }
  __syncthreads();
  if (tid < 256){
    float iv = invs;
    cs2[tid] = (f16x2){ (f16)(cpr[tid*2]*iv), (f16)(cpr[tid*2+1]*iv) };
  }
  __syncthreads();
  // gates: 64 rows x 8 lanes; both matvecs into one accumulator
  const int l8 = tid >> 3, q8 = tid & 7;
  const f16x8* wA = (const f16x8*)(Whh_h  + ((size_t)(b*64 + l8))*HID  + q8*128);
  const f16x8* wB = (const f16x8*)(Wihc_h + ((size_t)(b*64 + l8))*ENCD + q8*64);
  float acc = 0.f;
  #pragma unroll
  for (int i = 0; i < 16; ++i){
    f16x8 wv = wA[i];
    const f16x2* wp = (const f16x2*)&wv;
    int k2 = q8*64 + i*4;
    acc = __builtin_amdgcn_fdot2(wp[0], hs2[k2+0], acc, false);
    acc = __builtin_amdgcn_fdot2(wp[1], hs2[k2+1], acc, false);
    acc = __builtin_amdgcn_fdot2(wp[2], hs2[k2+2], acc, false);
    acc = __builtin_amdgcn_fdot2(wp[3], hs2[k2+3], acc, false);
  }
  #pragma unroll
  for (int i = 0; i < 8; ++i){
    f16x8 wv = wB[i];
    const f16x2* wp = (const f16x2*)&wv;
    int k2 = q8*32 + i*4;
    acc = __builtin_amdgcn_fdot2(wp[0], cs2[k2+0], acc, false);
    acc = __builtin_amdgcn_fdot2(wp[1], cs2[k2+1], acc, false);
    acc = __builtin_amdgcn_fdot2(wp[2], cs2[k2+2], acc, false);
    acc = __builtin_amdgcn_fdot2(wp[3], cs2[k2+3], acc, false);
  }
  acc += __shfl_xor(acc,1); acc += __shfl_xor(acc,2); acc += __shfl_xor(acc,4);
  if (q8 == 0) g2[l8] = acc + Gp[(size_t)t*4096 + b*64 + l8];
  __syncthreads();
  if (tid < 16){
    float gi = g2[tid], gf = g2[16+tid], gg = g2[32+tid], go = g2[48+tid];
    float cv = Cc[b*16 + tid];
    float cn = sigm(gf)*cv + sigm(gi)*tanh_f(gg);
    float hn = sigm(go)*tanh_f(cn);
    Cc[b*16 + tid] = cn;
    Hh[(size_t)(t+1)*HID + b*16 + tid] = hn;
    hnl[tid] = hn;
  }
  __syncthreads();
  if (tid < 128){
    const float* wr = Wa_h + (size_t)tid*HID + b*16;
    float a = 0.f;
    #pragma unroll
    for (int i4 = 0; i4 < 4; ++i4){
      float4 w4 = *reinterpret_cast<const float4*>(wr + i4*4);
      a += w4.x*hnl[i4*4] + w4.y*hnl[i4*4+1] + w4.z*hnl[i4*4+2] + w4.w*hnl[i4*4+3];
    }
    wahp[b*128 + tid] = a;
  }
}

// ---- epilogue: logits = H @ W_out^T + b_out (bf16 MFMA, f32 in/out) ----
__global__ __launch_bounds__(256) void k_gemm(const float* __restrict__ A, const float* __restrict__ B,
                                              const float* __restrict__ bias, float* __restrict__ C){
  int bn = blockIdx.x, bm = blockIdx.y;
  int tid = threadIdx.x;
  int wid = tid>>6, lane = tid&63;
  int wr = wid>>1, wc = wid&1;
  int rowf = lane&15, kg = lane>>4;
  const int m_base = bm*128 + wr*64;
  const int n_base = bn*128 + wc*64;
  const float* Ap = A + (size_t)(m_base + rowf)*HID + kg*8;
  const float* Bp = B + (size_t)(n_base + rowf)*HID + kg*8;
  f32x4 acc[4][4];
  #pragma unroll
  for (int i=0;i<4;i++)
    #pragma unroll
    for (int jv=0;jv<4;jv++) acc[i][jv] = (f32x4){0.f,0.f,0.f,0.f};
  for (int kk=0; kk<HID; kk+=32){
    bf16x8v av[4], bv[4];
    #pragma unroll
    for (int mt=0;mt<4;mt++) av[mt] = cvt8(Ap + (size_t)mt*16*HID + kk);
    #pragma unroll
    for (int nt=0;nt<4;nt++) bv[nt] = cvt8(Bp + (size_t)nt*16*HID + kk);
    #pragma unroll
    for (int mt=0;mt<4;mt++)
      #pragma unroll
      for (int nt=0;nt<4;nt++)
        acc[mt][nt] = __builtin_amdgcn_mfma_f32_16x16x32_bf16(av[mt], bv[nt], acc[mt][nt], 0,0,0);
  }
  #pragma unroll
  for (int mt=0;mt<4;mt++){
    #pragma unroll
    for (int nt=0;nt<4;nt++){
      int n = n_base + nt*16 + rowf;
      float bo = bias[n];
      #pragma unroll
      for (int i=0;i<4;i++){
        int m = m_base + mt*16 + kg*4 + i;
        C[(size_t)m*VOCAB + n] = acc[mt][nt][i] + bo;
      }
    }
  }
}

// ---- epilogue: attn = P * invden, in place on d_out ----
__global__ void k_attnorm(float* __restrict__ out, const float* __restrict__ invden){
  int idx = blockIdx.x*256 + threadIdx.x;
  out[idx] = out[idx]*invden[idx>>10];
}

extern "C" void kernel_launch(void* const* d_in, const int* in_sizes, int n_in,
                              void* d_out, int out_size, void* d_ws, size_t ws_size,
                              hipStream_t stream){
  const float* enc    = (const float*)d_in[0];
  const float* h0     = (const float*)d_in[1];
  const float* c0     = (const float*)d_in[2];
  const int*   sos    = (const int*)d_in[3];
  const int*   tgt    = (const int*)d_in[4];
  const float* embt   = (const float*)d_in[5];
  const float* Wa_enc = (const float*)d_in[6];
  const float* Wa_h   = (const float*)d_in[7];
  const float* v_a    = (const float*)d_in[8];
  const float* W_ih   = (const float*)d_in[9];
  const float* W_hh   = (const float*)d_in[10];
  const float* b_ih   = (const float*)d_in[11];
  const float* b_hh   = (const float*)d_in[12];
  const float* W_out  = (const float*)d_in[13];
  const float* b_out  = (const float*)d_in[14];

  float* ws    = (float*)d_ws;
  f16*   eph   = (f16*)(ws + OFF_EPH);
  float* Gp    = ws + OFF_G;
  float* Hh    = ws + OFF_HH;
  float* Cc    = ws + OFF_CC;
  float* invd  = ws + OFF_INVD;
  float* ctxp  = ws + OFF_CTXP;
  float* denp  = ws + OFF_DENP;
  float* wahp  = ws + OFF_WAHP;
  unsigned* pslots = (unsigned*)(ws + OFF_PROBE);
  f16* Whh_h   = (f16*)(ws + OFF_WHH);
  f16* Wihc_h  = (f16*)(ws + OFF_WIHC);
  f16* enc_h   = (f16*)(ws + OFF_ENCH);

  float* out_logits = (float*)d_out;
  float* out_attn   = out_logits + (size_t)TGT*VOCAB;

  k_encproj <<<64, 128, 0, stream>>>(enc, Wa_enc, eph);
  k_gbase   <<<dim3(16, 32), 256, 0, stream>>>(sos, tgt, embt, W_ih, b_ih, b_hh, Gp);
  k_cvt_whh <<<4096, 128, 0, stream>>>(W_hh, Whh_h);
  k_cvt_wihc<<<4096, 64, 0, stream>>>(W_ih, Wihc_h);
  k_cvt_ench<<<1024, 64, 0, stream>>>(enc, enc_h);
  k_prep0   <<<64, 128, 0, stream>>>(h0, c0, Wa_h, Hh, Cc, wahp, pslots);
  k_barprobe<<<32, 256, 0, stream>>>(pslots);     // µbench: dur/128 = barrier cost

  for (int t = 0; t < TGT; ++t){
    k_attn<<<NBA, 1024, 0, stream>>>(t, eph, enc_h, v_a, wahp, out_attn, ctxp, denp);
    k_step<<<NBS, 512, 0, stream>>>(t, Whh_h, Wihc_h, Wa_h, Gp, ctxp, denp, Hh, Cc, wahp, invd);
  }

  k_gemm   <<<dim3(250, 4), 256, 0, stream>>>(Hh + HID, W_out, b_out, out_logits);
  k_attnorm<<<2048, 256, 0, stream>>>(out_attn, invd);
}